// Round 6
// baseline (490.193 us; speedup 1.0000x reference)
//
#include <hip/hip_runtime.h>
#include <hip/hip_bf16.h>

#define HD   64
#define SEQ  2048
#define NB   256
#define TWOH 128
#define NCH  32   // SEQ / 64

typedef float v4f __attribute__((ext_vector_type(4)));

// ws float layout:
// [0,4096)      k_tab  (normalized k per token)
// [4096,8192)   v_tab
// [8192,12288)  q_tab
// [12288,12352) thr2   ((0.4*||v_t||)^2)
// [12352]       bf16 input flag
// [12416,16512) G = K K^T  (Gram of normalized keys)

#define WS_V    4096
#define WS_Q    8192
#define WS_THR  12288
#define WS_FLAG 12352
#define WS_G    12416

// ---- DPP wave-total: sum across 64 lanes, broadcast via lane 63 ----
template <int CTRL>
__device__ __forceinline__ float dpp_add(float x) {
    int y = __builtin_amdgcn_update_dpp(0, __builtin_bit_cast(int, x),
                                        CTRL, 0xF, 0xF, true);
    return x + __builtin_bit_cast(float, y);
}

__device__ __forceinline__ float wave_total(float x) {
    x = dpp_add<0x111>(x);   // row_shr:1
    x = dpp_add<0x112>(x);   // row_shr:2
    x = dpp_add<0x114>(x);   // row_shr:4
    x = dpp_add<0x118>(x);   // row_shr:8
    x = dpp_add<0x142>(x);   // row_bcast:15
    x = dpp_add<0x143>(x);   // row_bcast:31 -> lane 63 has full sum
    return __builtin_bit_cast(float,
        __builtin_amdgcn_readlane(__builtin_bit_cast(int, x), 63));
}

__device__ __forceinline__ float bcastf(float v, int l) {
    return __builtin_bit_cast(float,
        __builtin_amdgcn_readlane(__builtin_bit_cast(int, v), l));
}

// f32 data read as bf16 at even 16-bit halves -> mantissa bits land in the
// exponent field -> huge/NaN values. True bf16 inputs are ~0.05-scale.
// Uses lane (0..63) only -> identical result on every wave of the block.
__device__ __forceinline__ bool detect_bf16(const void* embed, int lane) {
    const unsigned short* u = (const unsigned short*)embed;
    int bad = 0;
    for (int i = 2 * lane; i < 4096; i += 128) {
        float v = __uint_as_float(((unsigned int)u[i]) << 16);
        if (!(fabsf(v) < 1e4f)) bad = 1;
    }
    return !__any(bad);
}

template <bool BF>
__device__ __forceinline__ float ldf(const void* p, int i) {
    if (BF) return __bfloat162float(((const __hip_bfloat16*)p)[i]);
    return ((const float*)p)[i];
}

// Single block, 1024 threads = 16 waves. Wave w handles tokens 4w..4w+3
// (lock-step __syncthreads across all waves), then computes 4 rows of
// G = K K^T from the LDS copy of K. Fuses the old gram_kernel (-1 launch).
template <bool BF>
__device__ void precompute_body(const void* embed, const void* w1, const void* b1,
                                const void* w2, const void* b2, const void* ln_g,
                                const void* ln_b, const void* wk, const void* wv,
                                const void* wq, float* __restrict__ ws) {
    const int tid = threadIdx.x, wave = tid >> 6, lane = tid & 63;
    __shared__ float k_sh[64 * 65];          // K rows, padded stride 65
    __shared__ float sh_h[16][HD];           // per-wave scratch
    __shared__ float sh_u[16][TWOH];
    float* shh = sh_h[wave];
    float* shu = sh_u[wave];

    #pragma unroll 1
    for (int it = 0; it < 4; ++it) {
        const int t = wave * 4 + it;
        float h = ldf<BF>(embed, t * HD + lane);
        shh[lane] = h;
        __syncthreads();

        // FFN layer 1: u = relu(h @ w1 + b1); lane -> outputs (lane, lane+64)
        float a0 = 0.f, a1 = 0.f, a2 = 0.f, a3 = 0.f;
        #pragma unroll 16
        for (int j = 0; j < HD; j += 2) {
            float h0 = shh[j], h1 = shh[j + 1];
            a0 = fmaf(h0, ldf<BF>(w1, j * TWOH + lane), a0);
            a1 = fmaf(h0, ldf<BF>(w1, j * TWOH + lane + HD), a1);
            a2 = fmaf(h1, ldf<BF>(w1, (j + 1) * TWOH + lane), a2);
            a3 = fmaf(h1, ldf<BF>(w1, (j + 1) * TWOH + lane + HD), a3);
        }
        shu[lane]      = fmaxf(a0 + a2 + ldf<BF>(b1, lane), 0.f);
        shu[lane + HD] = fmaxf(a1 + a3 + ldf<BF>(b1, lane + HD), 0.f);
        __syncthreads();

        // FFN layer 2 + residual
        float f0 = 0.f, f1 = 0.f, f2 = 0.f, f3 = 0.f;
        #pragma unroll 16
        for (int e = 0; e < TWOH; e += 4) {
            f0 = fmaf(shu[e + 0], ldf<BF>(w2, (e + 0) * HD + lane), f0);
            f1 = fmaf(shu[e + 1], ldf<BF>(w2, (e + 1) * HD + lane), f1);
            f2 = fmaf(shu[e + 2], ldf<BF>(w2, (e + 2) * HD + lane), f2);
            f3 = fmaf(shu[e + 3], ldf<BF>(w2, (e + 3) * HD + lane), f3);
        }
        float y = h + (f0 + f1) + (f2 + f3) + ldf<BF>(b2, lane);

        // LayerNorm over 64 dims (eps 1e-5), in-wave DPP reductions
        float mu  = wave_total(y) * 0.015625f;
        float dvv = y - mu;
        float var = wave_total(dvv * dvv) * 0.015625f;
        float hn  = fmaf(dvv * (1.f / sqrtf(var + 1e-5f)), ldf<BF>(ln_g, lane),
                         ldf<BF>(ln_b, lane));

        __syncthreads();
        shh[lane] = hn;
        __syncthreads();

        // k/v/q projections
        float k0 = 0.f, k1 = 0.f, v0 = 0.f, v1 = 0.f, q0 = 0.f, q1 = 0.f;
        #pragma unroll 16
        for (int j = 0; j < HD; j += 2) {
            float h0 = shh[j], h1 = shh[j + 1];
            k0 = fmaf(h0, ldf<BF>(wk, j * HD + lane), k0);
            v0 = fmaf(h0, ldf<BF>(wv, j * HD + lane), v0);
            q0 = fmaf(h0, ldf<BF>(wq, j * HD + lane), q0);
            k1 = fmaf(h1, ldf<BF>(wk, (j + 1) * HD + lane), k1);
            v1 = fmaf(h1, ldf<BF>(wv, (j + 1) * HD + lane), v1);
            q1 = fmaf(h1, ldf<BF>(wq, (j + 1) * HD + lane), q1);
        }
        float k = k0 + k1, v = v0 + v1, q = q0 + q1;
        float nk = sqrtf(wave_total(k * k));
        k /= fmaxf(nk, 1e-12f);               // k / max(||k||, NORM_EPS)
        float nv2 = wave_total(v * v);

        ws[t * HD + lane]        = k;
        ws[WS_V + t * HD + lane] = v;
        ws[WS_Q + t * HD + lane] = q;
        k_sh[t * 65 + lane] = k;
        if (lane == 0) ws[WS_THR + t] = 0.16f * nv2;   // (0.4*||v||)^2
    }
    __syncthreads();

    // G[t][u] = k_t . k_u  — wave handles rows 4w..4w+3, lane = u.
    #pragma unroll 1
    for (int it = 0; it < 4; ++it) {
        const int t = wave * 4 + it;
        const float* kt = &k_sh[t * 65];      // uniform row -> LDS broadcast
        const float* ku = &k_sh[lane * 65];   // stride-65 -> conflict-free
        float g0 = 0.f, g1 = 0.f, g2 = 0.f, g3 = 0.f;
        #pragma unroll
        for (int j = 0; j < HD; j += 4) {
            g0 = fmaf(kt[j + 0], ku[j + 0], g0);
            g1 = fmaf(kt[j + 1], ku[j + 1], g1);
            g2 = fmaf(kt[j + 2], ku[j + 2], g2);
            g3 = fmaf(kt[j + 3], ku[j + 3], g3);
        }
        ws[WS_G + t * HD + lane] = (g0 + g1) + (g2 + g3);
    }
    if (tid == 0) ws[WS_FLAG] = BF ? 1.f : 0.f;
}

__global__ __launch_bounds__(1024) void precompute_kernel(
    const void* embed, const void* w1, const void* b1, const void* w2,
    const void* b2, const void* ln_g, const void* ln_b, const void* wk,
    const void* wv, const void* wq, float* __restrict__ ws) {
    if (detect_bf16(embed, threadIdx.x & 63))
        precompute_body<true>(embed, w1, b1, w2, b2, ln_g, ln_b, wk, wv, wq, ws);
    else
        precompute_body<false>(embed, w1, b1, w2, b2, ln_g, ln_b, wk, wv, wq, ws);
}

// One wave per batch. Lane t owns token t's residual dv_t (16 v4f regs).
// nd2 (lane-local) -> fireset = ballot(nd2 > thr2) covers all 64 tokens.
// Fire on t: delta_t broadcast via v_readlane from lane t's dv registers
// (register SSA dependency -> no LDS round trip, no R4-style memory hazard),
// interleaved with packed-f32 FMAs:
//   dv_u -= G[t][u] * delta       (g per-lane from LDS, load overlaps readlanes)
//   R    += cq_t * delta          (cq_t = k_t . q; q known from last token)
//   nd2  = ||dv_u||^2
// Readout: out = relu(R) @ wo + bo   (R identical on all lanes).
__global__ __launch_bounds__(64, 1) void scan_kernel(
    const int* __restrict__ x, const float* __restrict__ ws,
    const void* __restrict__ wo, const void* __restrict__ bo,
    void* __restrict__ out) {
    const int b = blockIdx.x, lane = threadIdx.x;
    __shared__ __align__(16) float g_lds[4096];
    __shared__ int tok_lds[SEQ];

    // stage G + token stream (coalesced)
    #pragma unroll
    for (int i = 0; i < 16; ++i) {
        int o = i * 256 + lane * 4;
        *(float4*)&g_lds[o] = *(const float4*)&ws[WS_G + o];
    }
    const int* xr = x + b * SEQ;
    #pragma unroll
    for (int c = 0; c < NCH; ++c) tok_lds[c * 64 + lane] = xr[c * 64 + lane];

    const float thr2 = ws[WS_THR + lane];
    const bool  bf   = ws[WS_FLAG] != 0.f;

    // cq_lane = k_lane . q_{last token}
    const int tl = xr[SEQ - 1];
    const float* qrow = ws + WS_Q + tl * HD;
    const float* krow = ws + lane * HD;
    float c0 = 0.f, c1 = 0.f, c2 = 0.f, c3 = 0.f;
    #pragma unroll
    for (int j = 0; j < HD; j += 4) {
        float4 kv = *(const float4*)&krow[j];
        c0 = fmaf(qrow[j + 0], kv.x, c0);
        c1 = fmaf(qrow[j + 1], kv.y, c1);
        c2 = fmaf(qrow[j + 2], kv.z, c2);
        c3 = fmaf(qrow[j + 3], kv.w, c3);
    }
    const float cq = (c0 + c1) + (c2 + c3);

    // dv = v_lane (M = 0); R = 0; nd2 = ||dv||^2
    v4f dv[16], R[16];
    const float* vr = ws + WS_V + lane * HD;
    v4f acc = {0.f, 0.f, 0.f, 0.f};
    #pragma unroll
    for (int i = 0; i < 16; ++i) {
        float4 vv = *(const float4*)&vr[i * 4];
        dv[i] = (v4f){vv.x, vv.y, vv.z, vv.w};
        R[i]  = (v4f){0.f, 0.f, 0.f, 0.f};
        acc   = __builtin_elementwise_fma(dv[i], dv[i], acc);
    }
    float nd2 = (acc.x + acc.y) + (acc.z + acc.w);
    __syncthreads();
    unsigned long long fireset = __ballot(nd2 > thr2);

    int chunk = tok_lds[lane];
    #pragma unroll 1
    for (int c = 0; c < NCH; ++c) {
        int nxt = 0;
        if (c + 1 < NCH) nxt = tok_lds[(c + 1) * 64 + lane];
        unsigned long long pend = __ballot((int)((fireset >> chunk) & 1ull));
        while (pend) {
            const int s = __builtin_ctzll(pend);
            const int t = __builtin_amdgcn_readlane(chunk, s);
            const float g   = g_lds[t * HD + lane];   // overlaps readlanes
            const float cqt = bcastf(cq, t);
            const v4f gs  = {-g, -g, -g, -g};
            const v4f cqs = {cqt, cqt, cqt, cqt};
            v4f q4 = {0.f, 0.f, 0.f, 0.f};
            #pragma unroll
            for (int i = 0; i < 16; ++i) {
                v4f sve;                                   // delta_t[4i..4i+4)
                sve.x = bcastf(dv[i].x, t);                // reads PRE-update dv
                sve.y = bcastf(dv[i].y, t);
                sve.z = bcastf(dv[i].z, t);
                sve.w = bcastf(dv[i].w, t);
                dv[i] = __builtin_elementwise_fma(gs, sve, dv[i]);
                R[i]  = __builtin_elementwise_fma(cqs, sve, R[i]);
                q4    = __builtin_elementwise_fma(dv[i], dv[i], q4);
            }
            nd2 = (q4.x + q4.y) + (q4.z + q4.w);
            fireset = __ballot(nd2 > thr2);
            const unsigned long long above =
                (s >= 63) ? 0ull : (~0ull << (s + 1));
            pend = __ballot((int)((fireset >> chunk) & 1ull)) & above;
        }
        chunk = nxt;
    }

    // out[b][c] = sum_j relu(R[j]) * wo[j][c] + bo[c]   (lane = c; R uniform)
    if (bf) {
        float acc2 = __bfloat162float(((const __hip_bfloat16*)bo)[lane]);
        #pragma unroll
        for (int i = 0; i < 16; ++i) {
            #pragma unroll
            for (int e = 0; e < 4; ++e) {
                float rj = fmaxf(R[i][e], 0.f);
                acc2 = fmaf(rj,
                    __bfloat162float(((const __hip_bfloat16*)wo)[(i * 4 + e) * HD + lane]),
                    acc2);
            }
        }
        ((__hip_bfloat16*)out)[b * HD + lane] = __float2bfloat16(acc2);
    } else {
        float acc2 = ((const float*)bo)[lane];
        #pragma unroll
        for (int i = 0; i < 16; ++i) {
            #pragma unroll
            for (int e = 0; e < 4; ++e) {
                float rj = fmaxf(R[i][e], 0.f);
                acc2 = fmaf(rj, ((const float*)wo)[(i * 4 + e) * HD + lane], acc2);
            }
        }
        ((float*)out)[b * HD + lane] = acc2;
    }
}

extern "C" void kernel_launch(void* const* d_in, const int* in_sizes, int n_in,
                              void* d_out, int out_size, void* d_ws, size_t ws_size,
                              hipStream_t stream) {
    const int* x      = (const int*)d_in[0];
    const void* embed = d_in[1];
    const void* w1    = d_in[2];
    const void* b1    = d_in[3];
    const void* w2    = d_in[4];
    const void* b2    = d_in[5];
    const void* ln_g  = d_in[6];
    const void* ln_b  = d_in[7];
    const void* wk    = d_in[8];
    const void* wv    = d_in[9];
    const void* wq    = d_in[10];
    const void* wo    = d_in[11];
    const void* bo    = d_in[12];
    float* ws = (float*)d_ws;

    precompute_kernel<<<1, 1024, 0, stream>>>(embed, w1, b1, w2, b2, ln_g, ln_b,
                                              wk, wv, wq, ws);
    scan_kernel<<<NB, 64, 0, stream>>>(x, ws, wo, bo, d_out);
}

// Round 7
// 421.455 us; speedup vs baseline: 1.1631x; 1.1631x over previous
//
#include <hip/hip_runtime.h>
#include <hip/hip_bf16.h>

#define HD   64
#define SEQ  2048
#define NB   256
#define TWOH 128
#define NCH  32   // SEQ / 64

typedef float v4f __attribute__((ext_vector_type(4)));

// ws float layout:
// [0,4096)      k_tab  (normalized k per token)
// [4096,8192)   v_tab
// [8192,12288)  q_tab
// [12288,12352) thr2   ((0.4*||v_t||)^2)
// [12352]       bf16 input flag

#define WS_V    4096
#define WS_Q    8192
#define WS_THR  12288
#define WS_FLAG 12352

// ---- DPP wave-total: sum across 64 lanes, broadcast via lane 63 ----
template <int CTRL>
__device__ __forceinline__ float dpp_add(float x) {
    int y = __builtin_amdgcn_update_dpp(0, __builtin_bit_cast(int, x),
                                        CTRL, 0xF, 0xF, true);
    return x + __builtin_bit_cast(float, y);
}

__device__ __forceinline__ float wave_total(float x) {
    x = dpp_add<0x111>(x);   // row_shr:1
    x = dpp_add<0x112>(x);   // row_shr:2
    x = dpp_add<0x114>(x);   // row_shr:4
    x = dpp_add<0x118>(x);   // row_shr:8
    x = dpp_add<0x142>(x);   // row_bcast:15
    x = dpp_add<0x143>(x);   // row_bcast:31 -> lane 63 has full sum
    return __builtin_bit_cast(float,
        __builtin_amdgcn_readlane(__builtin_bit_cast(int, x), 63));
}

__device__ __forceinline__ float bcastf(float v, int l) {
    return __builtin_bit_cast(float,
        __builtin_amdgcn_readlane(__builtin_bit_cast(int, v), l));
}

__device__ __forceinline__ float bpermf(int byte_addr, float v) {
    return __builtin_bit_cast(float,
        __builtin_amdgcn_ds_bpermute(byte_addr, __builtin_bit_cast(int, v)));
}

// f32 data read as bf16 at even 16-bit halves -> huge/NaN values.
__device__ __forceinline__ bool detect_bf16(const void* embed) {
    const unsigned short* u = (const unsigned short*)embed;
    int bad = 0;
    for (int i = 2 * threadIdx.x; i < 4096; i += 128) {
        float v = __uint_as_float(((unsigned int)u[i]) << 16);
        if (!(fabsf(v) < 1e4f)) bad = 1;
    }
    return !__any(bad);
}

template <bool BF>
__device__ __forceinline__ float ldf(const void* p, int i) {
    if (BF) return __bfloat162float(((const __hip_bfloat16*)p)[i]);
    return ((const float*)p)[i];
}

// 64 blocks, one token each (parallel across CUs — R6's single-block fusion
// serialized this onto 1 CU and cost ~130 µs; reverted).
template <bool BF>
__device__ void precompute_body(const void* embed, const void* w1, const void* b1,
                                const void* w2, const void* b2, const void* ln_g,
                                const void* ln_b, const void* wk, const void* wv,
                                const void* wq, float* __restrict__ ws) {
    const int t = blockIdx.x, d = threadIdx.x;
    __shared__ float sh_h[HD];
    __shared__ float sh_u[TWOH];

    float h = ldf<BF>(embed, t * HD + d);
    sh_h[d] = h;
    __syncthreads();

    float a0 = 0.f, a1 = 0.f, a2 = 0.f, a3 = 0.f;
    #pragma unroll 16
    for (int j = 0; j < HD; j += 2) {
        float h0 = sh_h[j], h1 = sh_h[j + 1];
        a0 = fmaf(h0, ldf<BF>(w1, j * TWOH + d), a0);
        a1 = fmaf(h0, ldf<BF>(w1, j * TWOH + d + HD), a1);
        a2 = fmaf(h1, ldf<BF>(w1, (j + 1) * TWOH + d), a2);
        a3 = fmaf(h1, ldf<BF>(w1, (j + 1) * TWOH + d + HD), a3);
    }
    float u0 = fmaxf(a0 + a2 + ldf<BF>(b1, d), 0.f);
    float u1 = fmaxf(a1 + a3 + ldf<BF>(b1, d + HD), 0.f);
    sh_u[d] = u0;
    sh_u[d + HD] = u1;
    __syncthreads();

    float f0 = 0.f, f1 = 0.f, f2 = 0.f, f3 = 0.f;
    #pragma unroll 16
    for (int e = 0; e < TWOH; e += 4) {
        f0 = fmaf(sh_u[e + 0], ldf<BF>(w2, (e + 0) * HD + d), f0);
        f1 = fmaf(sh_u[e + 1], ldf<BF>(w2, (e + 1) * HD + d), f1);
        f2 = fmaf(sh_u[e + 2], ldf<BF>(w2, (e + 2) * HD + d), f2);
        f3 = fmaf(sh_u[e + 3], ldf<BF>(w2, (e + 3) * HD + d), f3);
    }
    float y = h + (f0 + f1) + (f2 + f3) + ldf<BF>(b2, d);

    float mu  = wave_total(y) * 0.015625f;
    float dvv = y - mu;
    float var = wave_total(dvv * dvv) * 0.015625f;
    float hn  = fmaf(dvv * (1.f / sqrtf(var + 1e-5f)), ldf<BF>(ln_g, d),
                     ldf<BF>(ln_b, d));

    __syncthreads();
    sh_h[d] = hn;
    __syncthreads();

    float k0 = 0.f, k1 = 0.f, v0 = 0.f, v1 = 0.f, q0 = 0.f, q1 = 0.f;
    #pragma unroll 16
    for (int j = 0; j < HD; j += 2) {
        float h0 = sh_h[j], h1 = sh_h[j + 1];
        k0 = fmaf(h0, ldf<BF>(wk, j * HD + d), k0);
        v0 = fmaf(h0, ldf<BF>(wv, j * HD + d), v0);
        q0 = fmaf(h0, ldf<BF>(wq, j * HD + d), q0);
        k1 = fmaf(h1, ldf<BF>(wk, (j + 1) * HD + d), k1);
        v1 = fmaf(h1, ldf<BF>(wv, (j + 1) * HD + d), v1);
        q1 = fmaf(h1, ldf<BF>(wq, (j + 1) * HD + d), q1);
    }
    float k = k0 + k1, v = v0 + v1, q = q0 + q1;
    float nk = sqrtf(wave_total(k * k));
    k /= fmaxf(nk, 1e-12f);                 // k / max(||k||, NORM_EPS)
    float nv2 = wave_total(v * v);

    ws[t * HD + d]        = k;
    ws[WS_V + t * HD + d] = v;
    ws[WS_Q + t * HD + d] = q;
    if (d == 0) ws[WS_THR + t] = 0.16f * nv2;   // (0.4*||v||)^2
    if (t == 0 && d == 0) ws[WS_FLAG] = BF ? 1.f : 0.f;
}

__global__ __launch_bounds__(64) void precompute_kernel(
    const void* embed, const void* w1, const void* b1, const void* w2,
    const void* b2, const void* ln_g, const void* ln_b, const void* wk,
    const void* wv, const void* wq, float* __restrict__ ws) {
    if (detect_bf16(embed))
        precompute_body<true>(embed, w1, b1, w2, b2, ln_g, ln_b, wk, wv, wq, ws);
    else
        precompute_body<false>(embed, w1, b1, w2, b2, ln_g, ln_b, wk, wv, wq, ws);
}

// One wave per batch. Lane t owns token t's residual dv_t (16 v4f regs).
// G = K K^T built inline per block (~6 µs, replaces the gram launch + gap;
// lane u only reads G column u, which it wrote itself — no cross-lane dep).
// Fire on t: delta_t broadcast from lane t's registers — blocks 0..7 via
// v_readlane (VALU pipe), blocks 8..15 via ds_bpermute with uniform address
// (LDS pipe, issued before any dv update -> SSA-safe pre-update values,
// overlaps the VALU work). Packed-f32 FMAs:
//   dv_u -= G[t][u] * delta;  R += cq_t * delta;  nd2 = ||dv_u||^2
// Readout: out = relu(R) @ wo + bo  (R identical on all lanes).
__global__ __launch_bounds__(64, 1) void scan_kernel(
    const int* __restrict__ x, const float* __restrict__ ws,
    const void* __restrict__ wo, const void* __restrict__ bo,
    void* __restrict__ out) {
    const int b = blockIdx.x, lane = threadIdx.x;
    __shared__ __align__(16) float k_lds[4096];
    __shared__ __align__(16) float g_lds[4096];
    __shared__ int tok_lds[SEQ];

    // stage K + token stream (coalesced)
    #pragma unroll
    for (int i = 0; i < 16; ++i) {
        int o = i * 256 + lane * 4;
        *(float4*)&k_lds[o] = *(const float4*)&ws[o];
    }
    const int* xr = x + b * SEQ;
    #pragma unroll
    for (int c = 0; c < NCH; ++c) tok_lds[c * 64 + lane] = xr[c * 64 + lane];

    const float thr2 = ws[WS_THR + lane];
    const bool  bf   = ws[WS_FLAG] != 0.f;

    // k_lane into registers (global, L2-hot) + cq = k_lane . q_{last token}
    const int tl = xr[SEQ - 1];
    const float* qrow = ws + WS_Q + tl * HD;
    const float* krow = ws + lane * HD;
    v4f kreg[16];
    #pragma unroll
    for (int i = 0; i < 16; ++i) {
        float4 kv = *(const float4*)&krow[i * 4];
        kreg[i] = (v4f){kv.x, kv.y, kv.z, kv.w};
    }
    v4f cacc = {0.f, 0.f, 0.f, 0.f};
    #pragma unroll
    for (int i = 0; i < 16; ++i) {
        const float* qp = &qrow[i * 4];
        v4f qv = {qp[0], qp[1], qp[2], qp[3]};
        cacc = __builtin_elementwise_fma(qv, kreg[i], cacc);
    }
    const float cq = (cacc.x + cacc.y) + (cacc.z + cacc.w);
    __syncthreads();

    // Build G: G[t][lane] = k_t . k_lane  (kt rows = uniform LDS reads)
    #pragma unroll 1
    for (int t = 0; t < HD; ++t) {
        const float* kt = &k_lds[t * HD];
        v4f a = {0.f, 0.f, 0.f, 0.f};
        #pragma unroll
        for (int i = 0; i < 16; ++i) {
            const v4f kv = *(const v4f*)&kt[i * 4];
            a = __builtin_elementwise_fma(kv, kreg[i], a);
        }
        g_lds[t * HD + lane] = (a.x + a.y) + (a.z + a.w);
    }
    __syncthreads();

    // dv = v_lane (M = 0); R = 0; nd2 = ||dv||^2
    v4f dv[16], R[16];
    const float* vr = ws + WS_V + lane * HD;
    v4f acc = {0.f, 0.f, 0.f, 0.f};
    #pragma unroll
    for (int i = 0; i < 16; ++i) {
        float4 vv = *(const float4*)&vr[i * 4];
        dv[i] = (v4f){vv.x, vv.y, vv.z, vv.w};
        R[i]  = (v4f){0.f, 0.f, 0.f, 0.f};
        acc   = __builtin_elementwise_fma(dv[i], dv[i], acc);
    }
    float nd2 = (acc.x + acc.y) + (acc.z + acc.w);
    unsigned long long fireset = __ballot(nd2 > thr2);

    int chunk = tok_lds[lane];
    #pragma unroll 1
    for (int c = 0; c < NCH; ++c) {
        int nxt = 0;
        if (c + 1 < NCH) nxt = tok_lds[(c + 1) * 64 + lane];
        unsigned long long pend = __ballot((int)((fireset >> chunk) & 1ull));
        while (pend) {
            const int s = __builtin_ctzll(pend);
            const int t = __builtin_amdgcn_readlane(chunk, s);
            const float g   = g_lds[t * HD + lane];
            const float cqt = bcastf(cq, t);
            const v4f gs  = {-g, -g, -g, -g};
            const v4f cqs = {cqt, cqt, cqt, cqt};
            // LDS-pipe broadcast for blocks 8..15 (pre-update values, SSA)
            const int ba = t << 2;
            v4f bp[8];
            #pragma unroll
            for (int i = 0; i < 8; ++i) {
                bp[i].x = bpermf(ba, dv[8 + i].x);
                bp[i].y = bpermf(ba, dv[8 + i].y);
                bp[i].z = bpermf(ba, dv[8 + i].z);
                bp[i].w = bpermf(ba, dv[8 + i].w);
            }
            v4f q4 = {0.f, 0.f, 0.f, 0.f};
            // VALU-pipe broadcast for blocks 0..7 (overlaps bpermute latency)
            #pragma unroll
            for (int i = 0; i < 8; ++i) {
                v4f sve;
                sve.x = bcastf(dv[i].x, t);
                sve.y = bcastf(dv[i].y, t);
                sve.z = bcastf(dv[i].z, t);
                sve.w = bcastf(dv[i].w, t);
                dv[i] = __builtin_elementwise_fma(gs, sve, dv[i]);
                R[i]  = __builtin_elementwise_fma(cqs, sve, R[i]);
                q4    = __builtin_elementwise_fma(dv[i], dv[i], q4);
            }
            #pragma unroll
            for (int i = 0; i < 8; ++i) {
                const v4f sve = bp[i];
                dv[8 + i] = __builtin_elementwise_fma(gs, sve, dv[8 + i]);
                R[8 + i]  = __builtin_elementwise_fma(cqs, sve, R[8 + i]);
                q4        = __builtin_elementwise_fma(dv[8 + i], dv[8 + i], q4);
            }
            nd2 = (q4.x + q4.y) + (q4.z + q4.w);
            fireset = __ballot(nd2 > thr2);
            const unsigned long long above =
                (s >= 63) ? 0ull : (~0ull << (s + 1));
            pend = __ballot((int)((fireset >> chunk) & 1ull)) & above;
        }
        chunk = nxt;
    }

    // out[b][c] = sum_j relu(R[j]) * wo[j][c] + bo[c]   (lane = c; R uniform)
    if (bf) {
        float acc2 = __bfloat162float(((const __hip_bfloat16*)bo)[lane]);
        #pragma unroll
        for (int i = 0; i < 16; ++i) {
            #pragma unroll
            for (int e = 0; e < 4; ++e) {
                float rj = fmaxf(R[i][e], 0.f);
                acc2 = fmaf(rj,
                    __bfloat162float(((const __hip_bfloat16*)wo)[(i * 4 + e) * HD + lane]),
                    acc2);
            }
        }
        ((__hip_bfloat16*)out)[b * HD + lane] = __float2bfloat16(acc2);
    } else {
        float acc2 = ((const float*)bo)[lane];
        #pragma unroll
        for (int i = 0; i < 16; ++i) {
            #pragma unroll
            for (int e = 0; e < 4; ++e) {
                float rj = fmaxf(R[i][e], 0.f);
                acc2 = fmaf(rj, ((const float*)wo)[(i * 4 + e) * HD + lane], acc2);
            }
        }
        ((float*)out)[b * HD + lane] = acc2;
    }
}

extern "C" void kernel_launch(void* const* d_in, const int* in_sizes, int n_in,
                              void* d_out, int out_size, void* d_ws, size_t ws_size,
                              hipStream_t stream) {
    const int* x      = (const int*)d_in[0];
    const void* embed = d_in[1];
    const void* w1    = d_in[2];
    const void* b1    = d_in[3];
    const void* w2    = d_in[4];
    const void* b2    = d_in[5];
    const void* ln_g  = d_in[6];
    const void* ln_b  = d_in[7];
    const void* wk    = d_in[8];
    const void* wv    = d_in[9];
    const void* wq    = d_in[10];
    const void* wo    = d_in[11];
    const void* bo    = d_in[12];
    float* ws = (float*)d_ws;

    precompute_kernel<<<64, 64, 0, stream>>>(embed, w1, b1, w2, b2, ln_g, ln_b,
                                             wk, wv, wq, ws);
    scan_kernel<<<NB, 64, 0, stream>>>(x, ws, wo, bo, d_out);
}

// Round 8
// 284.162 us; speedup vs baseline: 1.7251x; 1.4832x over previous
//
#include <hip/hip_runtime.h>
#include <hip/hip_bf16.h>

#define HD   64
#define SEQ  2048
#define NB   256
#define TWOH 128
#define NCH  32   // SEQ / 64

typedef float v4f __attribute__((ext_vector_type(4)));

// ws float layout:
// [0,4096)      k_tab  (normalized k per token)
// [4096,8192)   v_tab
// [8192,12288)  q_tab
// [12288,12352) thr2   ((0.4*||v_t||)^2)
// [12352]       bf16 input flag

#define WS_V    4096
#define WS_Q    8192
#define WS_THR  12288
#define WS_FLAG 12352

// ---- DPP wave-total: sum across 64 lanes, broadcast via lane 63 ----
template <int CTRL>
__device__ __forceinline__ float dpp_add(float x) {
    int y = __builtin_amdgcn_update_dpp(0, __builtin_bit_cast(int, x),
                                        CTRL, 0xF, 0xF, true);
    return x + __builtin_bit_cast(float, y);
}

__device__ __forceinline__ float wave_total(float x) {
    x = dpp_add<0x111>(x);   // row_shr:1
    x = dpp_add<0x112>(x);   // row_shr:2
    x = dpp_add<0x114>(x);   // row_shr:4
    x = dpp_add<0x118>(x);   // row_shr:8
    x = dpp_add<0x142>(x);   // row_bcast:15
    x = dpp_add<0x143>(x);   // row_bcast:31 -> lane 63 has full sum
    return __builtin_bit_cast(float,
        __builtin_amdgcn_readlane(__builtin_bit_cast(int, x), 63));
}

__device__ __forceinline__ float bcastf(float v, int l) {
    return __builtin_bit_cast(float,
        __builtin_amdgcn_readlane(__builtin_bit_cast(int, v), l));
}

__device__ __forceinline__ float hsum4(v4f a) {
    return (a.x + a.y) + (a.z + a.w);
}

// f32 data read as bf16 at even 16-bit halves -> huge/NaN values.
__device__ __forceinline__ bool detect_bf16(const void* embed) {
    const unsigned short* u = (const unsigned short*)embed;
    int bad = 0;
    for (int i = 2 * threadIdx.x; i < 4096; i += 128) {
        float v = __uint_as_float(((unsigned int)u[i]) << 16);
        if (!(fabsf(v) < 1e4f)) bad = 1;
    }
    return !__any(bad);
}

template <bool BF>
__device__ __forceinline__ float ldf(const void* p, int i) {
    if (BF) return __bfloat162float(((const __hip_bfloat16*)p)[i]);
    return ((const float*)p)[i];
}

// 64 blocks, one token each (parallel across CUs).
template <bool BF>
__device__ void precompute_body(const void* embed, const void* w1, const void* b1,
                                const void* w2, const void* b2, const void* ln_g,
                                const void* ln_b, const void* wk, const void* wv,
                                const void* wq, float* __restrict__ ws) {
    const int t = blockIdx.x, d = threadIdx.x;
    __shared__ float sh_h[HD];
    __shared__ float sh_u[TWOH];

    float h = ldf<BF>(embed, t * HD + d);
    sh_h[d] = h;
    __syncthreads();

    float a0 = 0.f, a1 = 0.f, a2 = 0.f, a3 = 0.f;
    #pragma unroll 16
    for (int j = 0; j < HD; j += 2) {
        float h0 = sh_h[j], h1 = sh_h[j + 1];
        a0 = fmaf(h0, ldf<BF>(w1, j * TWOH + d), a0);
        a1 = fmaf(h0, ldf<BF>(w1, j * TWOH + d + HD), a1);
        a2 = fmaf(h1, ldf<BF>(w1, (j + 1) * TWOH + d), a2);
        a3 = fmaf(h1, ldf<BF>(w1, (j + 1) * TWOH + d + HD), a3);
    }
    float u0 = fmaxf(a0 + a2 + ldf<BF>(b1, d), 0.f);
    float u1 = fmaxf(a1 + a3 + ldf<BF>(b1, d + HD), 0.f);
    sh_u[d] = u0;
    sh_u[d + HD] = u1;
    __syncthreads();

    float f0 = 0.f, f1 = 0.f, f2 = 0.f, f3 = 0.f;
    #pragma unroll 16
    for (int e = 0; e < TWOH; e += 4) {
        f0 = fmaf(sh_u[e + 0], ldf<BF>(w2, (e + 0) * HD + d), f0);
        f1 = fmaf(sh_u[e + 1], ldf<BF>(w2, (e + 1) * HD + d), f1);
        f2 = fmaf(sh_u[e + 2], ldf<BF>(w2, (e + 2) * HD + d), f2);
        f3 = fmaf(sh_u[e + 3], ldf<BF>(w2, (e + 3) * HD + d), f3);
    }
    float y = h + (f0 + f1) + (f2 + f3) + ldf<BF>(b2, d);

    float mu  = wave_total(y) * 0.015625f;
    float dvv = y - mu;
    float var = wave_total(dvv * dvv) * 0.015625f;
    float hn  = fmaf(dvv * (1.f / sqrtf(var + 1e-5f)), ldf<BF>(ln_g, d),
                     ldf<BF>(ln_b, d));

    __syncthreads();
    sh_h[d] = hn;
    __syncthreads();

    float k0 = 0.f, k1 = 0.f, v0 = 0.f, v1 = 0.f, q0 = 0.f, q1 = 0.f;
    #pragma unroll 16
    for (int j = 0; j < HD; j += 2) {
        float h0 = sh_h[j], h1 = sh_h[j + 1];
        k0 = fmaf(h0, ldf<BF>(wk, j * HD + d), k0);
        v0 = fmaf(h0, ldf<BF>(wv, j * HD + d), v0);
        q0 = fmaf(h0, ldf<BF>(wq, j * HD + d), q0);
        k1 = fmaf(h1, ldf<BF>(wk, (j + 1) * HD + d), k1);
        v1 = fmaf(h1, ldf<BF>(wv, (j + 1) * HD + d), v1);
        q1 = fmaf(h1, ldf<BF>(wq, (j + 1) * HD + d), q1);
    }
    float k = k0 + k1, v = v0 + v1, q = q0 + q1;
    float nk = sqrtf(wave_total(k * k));
    k /= fmaxf(nk, 1e-12f);                 // k / max(||k||, NORM_EPS)
    float nv2 = wave_total(v * v);

    ws[t * HD + d]        = k;
    ws[WS_V + t * HD + d] = v;
    ws[WS_Q + t * HD + d] = q;
    if (d == 0) ws[WS_THR + t] = 0.16f * nv2;   // (0.4*||v||)^2
    if (t == 0 && d == 0) ws[WS_FLAG] = BF ? 1.f : 0.f;
}

__global__ __launch_bounds__(64) void precompute_kernel(
    const void* embed, const void* w1, const void* b1, const void* w2,
    const void* b2, const void* ln_g, const void* ln_b, const void* wk,
    const void* wv, const void* wq, float* __restrict__ ws) {
    if (detect_bf16(embed))
        precompute_body<true>(embed, w1, b1, w2, b2, ln_g, ln_b, wk, wv, wq, ws);
    else
        precompute_body<false>(embed, w1, b1, w2, b2, ln_g, ln_b, wk, wv, wq, ws);
}

// 4 waves per batch (1 per SIMD). Wave w owns components [16w,16w+16) of
// every token's residual: lane u holds dv_u[16w..16w+16) as 4 v4f.
// Fire on t: each wave broadcasts ITS quarter of delta_t from its own lane t
// (16 readlanes — no cross-wave data), updates dv/R quarters (24 pk_fma),
// computes a partial ||dv_u||^2, and the 4 partials are combined through a
// ping-pong LDS buffer with ONE __syncthreads per fire. All control state
// (chunk, fireset, pend) is computed redundantly and identically per wave.
__global__ __launch_bounds__(256, 1) void scan_kernel(
    const int* __restrict__ x, const float* __restrict__ ws,
    const void* __restrict__ wo, const void* __restrict__ bo,
    void* __restrict__ out) {
    const int b = blockIdx.x, tid = threadIdx.x;
    const int wv = tid >> 6, lane = tid & 63;
    __shared__ __align__(16) float k_lds[4096];
    __shared__ __align__(16) float g_lds[4096];
    __shared__ int   tok_lds[SEQ];
    __shared__ float pbuf[2][4][64];     // ping-pong nd2 partials
    __shared__ __align__(16) float rd_lds[64];

    // stage K + token stream (coalesced over 256 threads)
    #pragma unroll
    for (int i = 0; i < 4; ++i) {
        int o = i * 1024 + tid * 4;
        *(float4*)&k_lds[o] = *(const float4*)&ws[o];
    }
    const int* xr = x + b * SEQ;
    #pragma unroll
    for (int c = 0; c < 8; ++c) tok_lds[c * 256 + tid] = xr[c * 256 + tid];

    const float thr2 = ws[WS_THR + lane];
    const bool  bf   = ws[WS_FLAG] != 0.f;

    // k_lane full row into registers (global, L2-hot; identical across waves)
    v4f kreg[16];
    const float* krow = ws + lane * HD;
    #pragma unroll
    for (int i = 0; i < 16; ++i) {
        float4 kv = *(const float4*)&krow[i * 4];
        kreg[i] = (v4f){kv.x, kv.y, kv.z, kv.w};
    }
    // cq_lane = k_lane . q_{last token}
    const int tl = xr[SEQ - 1];
    const float* qrow = ws + WS_Q + tl * HD;
    v4f cacc = {0.f, 0.f, 0.f, 0.f};
    #pragma unroll
    for (int i = 0; i < 16; ++i) {
        const float* qp = &qrow[i * 4];
        v4f qv = {qp[0], qp[1], qp[2], qp[3]};
        cacc = __builtin_elementwise_fma(qv, kreg[i], cacc);
    }
    const float cq = hsum4(cacc);
    __syncthreads();                       // k_lds + tok_lds visible

    // G build: wave w computes rows [16w,16w+16): G[t][lane] = k_t . k_lane
    #pragma unroll 1
    for (int t0 = 0; t0 < 16; ++t0) {
        const int t = wv * 16 + t0;
        const float* kt = &k_lds[t * HD];
        v4f a = {0.f, 0.f, 0.f, 0.f};
        #pragma unroll
        for (int i = 0; i < 16; ++i) {
            const v4f kv = *(const v4f*)&kt[i * 4];
            a = __builtin_elementwise_fma(kv, kreg[i], a);
        }
        g_lds[t * HD + lane] = hsum4(a);
    }

    // dv quarter = v_lane[16wv..16wv+16); R quarter = 0; partial nd2
    v4f dv[4], R[4];
    const float* vr = ws + WS_V + lane * HD + wv * 16;
    v4f acc = {0.f, 0.f, 0.f, 0.f};
    #pragma unroll
    for (int i = 0; i < 4; ++i) {
        float4 vvv = *(const float4*)&vr[i * 4];
        dv[i] = (v4f){vvv.x, vvv.y, vvv.z, vvv.w};
        R[i]  = (v4f){0.f, 0.f, 0.f, 0.f};
        acc   = __builtin_elementwise_fma(dv[i], dv[i], acc);
    }
    pbuf[0][wv][lane] = hsum4(acc);
    int pp = 1;
    __syncthreads();                       // g_lds + pbuf[0] visible
    float nd2 = ((pbuf[0][0][lane] + pbuf[0][1][lane]) +
                 (pbuf[0][2][lane] + pbuf[0][3][lane]));
    unsigned long long fireset = __ballot(nd2 > thr2);

    int chunk = tok_lds[lane];
    #pragma unroll 1
    for (int c = 0; c < NCH; ++c) {
        int nxt = 0;
        if (c + 1 < NCH) nxt = tok_lds[(c + 1) * 64 + lane];
        unsigned long long pend = __ballot((int)((fireset >> chunk) & 1ull));
        while (pend) {
            const int s = __builtin_ctzll(pend);
            const int t = __builtin_amdgcn_readlane(chunk, s);
            const float g   = g_lds[t * HD + lane];
            const float cqt = bcastf(cq, t);
            const v4f gs  = {-g, -g, -g, -g};
            const v4f cqs = {cqt, cqt, cqt, cqt};
            v4f q4 = {0.f, 0.f, 0.f, 0.f};
            #pragma unroll
            for (int i = 0; i < 4; ++i) {
                v4f sve;                           // delta_t quarter (own regs)
                sve.x = bcastf(dv[i].x, t);
                sve.y = bcastf(dv[i].y, t);
                sve.z = bcastf(dv[i].z, t);
                sve.w = bcastf(dv[i].w, t);
                dv[i] = __builtin_elementwise_fma(gs, sve, dv[i]);
                R[i]  = __builtin_elementwise_fma(cqs, sve, R[i]);
                q4    = __builtin_elementwise_fma(dv[i], dv[i], q4);
            }
            pbuf[pp][wv][lane] = hsum4(q4);
            __syncthreads();                       // single barrier per fire
            nd2 = ((pbuf[pp][0][lane] + pbuf[pp][1][lane]) +
                   (pbuf[pp][2][lane] + pbuf[pp][3][lane]));
            pp ^= 1;                               // ping-pong: no 2nd barrier
            fireset = __ballot(nd2 > thr2);
            const unsigned long long above =
                (s >= 63) ? 0ull : (~0ull << (s + 1));
            pend = __ballot((int)((fireset >> chunk) & 1ull)) & above;
        }
        chunk = nxt;
    }

    // read = relu(R): wave w's lanes all hold components [16wv..16wv+16)
    if (lane == 0) {
        #pragma unroll
        for (int i = 0; i < 4; ++i) {
            v4f r = R[i];
            r.x = fmaxf(r.x, 0.f); r.y = fmaxf(r.y, 0.f);
            r.z = fmaxf(r.z, 0.f); r.w = fmaxf(r.w, 0.f);
            *(v4f*)&rd_lds[wv * 16 + i * 4] = r;
        }
    }
    __syncthreads();

    // out[b][c] = sum_j rd[j] * wo[j][c] + bo[c]  — wave 0 only (lane = c)
    if (wv == 0) {
        if (bf) {
            float acc2 = __bfloat162float(((const __hip_bfloat16*)bo)[lane]);
            #pragma unroll 8
            for (int j = 0; j < HD; ++j)
                acc2 = fmaf(rd_lds[j],
                    __bfloat162float(((const __hip_bfloat16*)wo)[j * HD + lane]),
                    acc2);
            ((__hip_bfloat16*)out)[b * HD + lane] = __float2bfloat16(acc2);
        } else {
            float acc2 = ((const float*)bo)[lane];
            #pragma unroll 8
            for (int j = 0; j < HD; ++j)
                acc2 = fmaf(rd_lds[j], ((const float*)wo)[j * HD + lane], acc2);
            ((float*)out)[b * HD + lane] = acc2;
        }
    }
}

extern "C" void kernel_launch(void* const* d_in, const int* in_sizes, int n_in,
                              void* d_out, int out_size, void* d_ws, size_t ws_size,
                              hipStream_t stream) {
    const int* x      = (const int*)d_in[0];
    const void* embed = d_in[1];
    const void* w1    = d_in[2];
    const void* b1    = d_in[3];
    const void* w2    = d_in[4];
    const void* b2    = d_in[5];
    const void* ln_g  = d_in[6];
    const void* ln_b  = d_in[7];
    const void* wk    = d_in[8];
    const void* wv    = d_in[9];
    const void* wq    = d_in[10];
    const void* wo    = d_in[11];
    const void* bo    = d_in[12];
    float* ws = (float*)d_ws;

    precompute_kernel<<<64, 64, 0, stream>>>(embed, w1, b1, w2, b2, ln_g, ln_b,
                                             wk, wv, wq, ws);
    scan_kernel<<<NB, 256, 0, stream>>>(x, ws, wo, bo, d_out);
}